// Round 14
// baseline (1763.945 us; speedup 1.0000x reference)
//
#include <hip/hip_runtime.h>
#include <hip/hip_bf16.h>
#include <cstdint>
#include <cstddef>

#define DEVI __device__ __forceinline__

typedef __attribute__((ext_vector_type(8))) short short8;
typedef __attribute__((ext_vector_type(4))) float f32x4;
using u16 = unsigned short;

constexpr int BSZ = 32, TSZ = 128, VSZ = 50257, HSZ = 1024;
constexpr int M4 = BSZ * TSZ;          // 4096 rows
constexpr int FH = 4 * HSZ;            // 4096 gate rows
constexpr long long OUT_LOGP = (long long)M4 * VSZ;
constexpr int NWRK = 192;              // 64 layer0 + 128 layer1 worker blocks
constexpr int NBLK = 256;              // + 64 converter/early-proj blocks
constexpr int LDSB = 147584;           // dynamic LDS bytes (lstm)
constexpr int LDBF = 50258;            // bf16 logit row stride
constexpr int NNT = 393;               // proj n-tiles
constexpr int CVT_PER = 20;            // early proj tiles per converter block
constexpr int CVTILES = 64 * CVT_PER;  // 1280 tiles done inside coop

// ---------- small helpers ----------
DEVI u16 f2bf(float f) {
  unsigned u = __float_as_uint(f);
  unsigned r = (u + 0x7fffu + ((u >> 16) & 1u)) >> 16;
  return (u16)r;
}
DEVI u16 f2bf_hw(float f) {
  __hip_bfloat16 h = __float2bfloat16(f);
  return __builtin_bit_cast(u16, h);
}
DEVI float bf2f(u16 u) { return __uint_as_float(((unsigned)u) << 16); }
DEVI float sigm(float x) { return 1.f / (1.f + __expf(-x)); }
DEVI float tanh_fast(float x) { return 1.f - 2.f / (1.f + __expf(2.f * x)); }

DEVI f32x4 mfma16(short8 a, short8 b, f32x4 c) {
  return __builtin_amdgcn_mfma_f32_16x16x32_bf16(a, b, c, 0, 0, 0);
}

DEVI void gld16(const void* g, void* l) {
  auto gp = (const __attribute__((address_space(1))) unsigned int*)g;
  auto lp = (__attribute__((address_space(3))) unsigned int*)l;
  __builtin_amdgcn_global_load_lds(gp, lp, 16, 0, 0);
}

// ---------- SAFE coherent primitives ----------
DEVI void cohld16x16(const u16* base, short8 (&d)[16]) {
  asm volatile(
      "global_load_dwordx4 %0, %16, off sc0 sc1\n\t"
      "global_load_dwordx4 %1, %16, off offset:64 sc0 sc1\n\t"
      "global_load_dwordx4 %2, %16, off offset:128 sc0 sc1\n\t"
      "global_load_dwordx4 %3, %16, off offset:192 sc0 sc1\n\t"
      "global_load_dwordx4 %4, %16, off offset:256 sc0 sc1\n\t"
      "global_load_dwordx4 %5, %16, off offset:320 sc0 sc1\n\t"
      "global_load_dwordx4 %6, %16, off offset:384 sc0 sc1\n\t"
      "global_load_dwordx4 %7, %16, off offset:448 sc0 sc1\n\t"
      "global_load_dwordx4 %8, %16, off offset:512 sc0 sc1\n\t"
      "global_load_dwordx4 %9, %16, off offset:576 sc0 sc1\n\t"
      "global_load_dwordx4 %10, %16, off offset:640 sc0 sc1\n\t"
      "global_load_dwordx4 %11, %16, off offset:704 sc0 sc1\n\t"
      "global_load_dwordx4 %12, %16, off offset:768 sc0 sc1\n\t"
      "global_load_dwordx4 %13, %16, off offset:832 sc0 sc1\n\t"
      "global_load_dwordx4 %14, %16, off offset:896 sc0 sc1\n\t"
      "global_load_dwordx4 %15, %16, off offset:960 sc0 sc1\n\t"
      "s_waitcnt vmcnt(0)"
      : "=&v"(d[0]), "=&v"(d[1]), "=&v"(d[2]), "=&v"(d[3]),
        "=&v"(d[4]), "=&v"(d[5]), "=&v"(d[6]), "=&v"(d[7]),
        "=&v"(d[8]), "=&v"(d[9]), "=&v"(d[10]), "=&v"(d[11]),
        "=&v"(d[12]), "=&v"(d[13]), "=&v"(d[14]), "=&v"(d[15])
      : "v"(base)
      : "memory");
}
DEVI void cohst2_u16(u16* p0, u16 v0, u16* p1, u16 v1) {
  asm volatile(
      "global_store_short %0, %2, off sc0 sc1\n\t"
      "global_store_short %1, %3, off sc0 sc1\n\t"
      "s_waitcnt vmcnt(0)"
      :: "v"(p0), "v"(p1), "v"((unsigned)v0), "v"((unsigned)v1)
      : "memory");
}
DEVI void cohst1_u16(u16* p0, u16 v0) {
  asm volatile(
      "global_store_short %0, %1, off sc0 sc1\n\t"
      "s_waitcnt vmcnt(0)"
      :: "v"(p0), "v"((unsigned)v0)
      : "memory");
}
DEVI void flagst(unsigned* p, unsigned v) {
  __hip_atomic_store(p, v, __ATOMIC_RELAXED, __HIP_MEMORY_SCOPE_AGENT);
}
DEVI unsigned flagld(const unsigned* p) {
  return __hip_atomic_load(p, __ATOMIC_RELAXED, __HIP_MEMORY_SCOPE_AGENT);
}

DEVI void wait64(const unsigned* f, unsigned g, int l) {
  while (!__all((int)(flagld(f + l) >= g))) __builtin_amdgcn_s_sleep(1);
}
DEVI void wait128(const unsigned* f, unsigned g, int l) {
  for (;;) {
    unsigned a = flagld(f + l);
    unsigned b = flagld(f + 64 + l);
    if (__all((int)((a >= g) && (b >= g)))) break;
    __builtin_amdgcn_s_sleep(1);
  }
}

// ---------- prep (merged) ----------
__global__ void prep_all(const float* __restrict__ bih, const float* __restrict__ bhh,
                         float* __restrict__ bias0, float* __restrict__ rowsum,
                         unsigned* __restrict__ bar, const float* __restrict__ h0,
                         u16* __restrict__ H0, u16* __restrict__ h1init) {
  int i = blockIdx.x * 256 + threadIdx.x;   // 0..32767
  H0[i] = f2bf(h0[i]);
  h1init[i] = f2bf(h0[BSZ * HSZ + i]);
  if (i < FH) { bias0[i] = bih[i] + bhh[i]; rowsum[i] = 0.f; }
  if (i < 1024) bar[i] = 0u;
}

__global__ void cvt_bf16(const float* __restrict__ src, u16* __restrict__ dst, int n4) {
  int i = blockIdx.x * blockDim.x + threadIdx.x;
  int stride = gridDim.x * blockDim.x;
  for (; i < n4; i += stride) {
    float4 v = ((const float4*)src)[i];
    ushort4 o; o.x = f2bf(v.x); o.y = f2bf(v.y); o.z = f2bf(v.z); o.w = f2bf(v.w);
    ((ushort4*)dst)[i] = o;
  }
}

__global__ __launch_bounds__(256) void embed_kernel(const int* __restrict__ tok,
                                                    const float* __restrict__ emb,
                                                    u16* __restrict__ X) {
  int m = blockIdx.x;                // m = t*32 + b
  int t = m >> 5, b = m & 31;
  int token = tok[b * TSZ + t];
  const float4* src = (const float4*)(emb + (size_t)token * HSZ);
  int i = threadIdx.x;
  float4 v = src[i];
  ushort4 o; o.x = f2bf(v.x); o.y = f2bf(v.y); o.z = f2bf(v.z); o.w = f2bf(v.w);
  *(ushort4*)(X + (size_t)m * HSZ + i * 4) = o;
}

// ---------- 128x128 bf16 MFMA GEMM tile (device fn, shared coop/standalone) ----------
// EPI 1: C f32, LDS-staged full-line stores + bias[col] + rowsum atomics.
// EPI 2: C bf16 + bias[row] (G0T).
// EPI 3: C bf16, LDS-staged coalesced stores + bias[col] + rowsum atomics.
// TMAJ: A rows are t-major (t*32+b); C/rowsum remapped to out-row b*T+t.
template <int EPI, bool BCVT, bool TMAJ>
DEVI void gemm_tile(char* smemg, const u16* __restrict__ A, const void* __restrict__ Bsrc,
                    void* __restrict__ Cout, const float* __restrict__ bias,
                    float* __restrict__ rowsum, int m0, int n0, int N, int K, int ldc) {
  u16* As = (u16*)smemg;                 // [128][32] bf16 (K-loop)
  u16* Bs = (u16*)(smemg + 8192);        // [128][32] bf16 (K-loop)
  float* epi = (float*)smemg;            // [4 waves][16][64] f32 (epilogue, aliases)
  const int tid = threadIdx.x;
  const int l = tid & 63, wid = tid >> 6;
  const int wm = wid >> 1, wn = wid & 1;

  const int srow = tid >> 2, sq = tid & 3;
  const int arow0 = m0 + srow, arow1 = m0 + 64 + srow;
  int brow0 = n0 + srow;      if (brow0 > N - 1) brow0 = N - 1;
  int brow1 = n0 + 64 + srow; if (brow1 > N - 1) brow1 = N - 1;

  const u16* Bbf = (const u16*)Bsrc;
  const float* Bf32 = (const float*)Bsrc;
  u16* AsW = As + (size_t)(tid >> 6) * 512;
  u16* BsW = Bs + (size_t)(tid >> 6) * 512;

  f32x4 acc[4][4];
  f32x4 z = {0.f, 0.f, 0.f, 0.f};
#pragma unroll
  for (int a = 0; a < 4; ++a)
#pragma unroll
    for (int b = 0; b < 4; ++b) acc[a][b] = z;

  for (int k0 = 0; k0 < K; k0 += 32) {
    gld16(A + (size_t)arow0 * K + k0 + sq * 8, AsW);
    gld16(A + (size_t)arow1 * K + k0 + sq * 8, AsW + 2048);
    if (!BCVT) {
      gld16(Bbf + (size_t)brow0 * K + k0 + sq * 8, BsW);
      gld16(Bbf + (size_t)brow1 * K + k0 + sq * 8, BsW + 2048);
    } else {
      const float* s0 = Bf32 + (size_t)brow0 * K + k0 + sq * 8;
      const float* s1 = Bf32 + (size_t)brow1 * K + k0 + sq * 8;
      float4 x0 = *(const float4*)s0, y0 = *(const float4*)(s0 + 4);
      float4 x1 = *(const float4*)s1, y1 = *(const float4*)(s1 + 4);
      short8 v0, v1;
      v0[0]=(short)f2bf(x0.x); v0[1]=(short)f2bf(x0.y); v0[2]=(short)f2bf(x0.z); v0[3]=(short)f2bf(x0.w);
      v0[4]=(short)f2bf(y0.x); v0[5]=(short)f2bf(y0.y); v0[6]=(short)f2bf(y0.z); v0[7]=(short)f2bf(y0.w);
      v1[0]=(short)f2bf(x1.x); v1[1]=(short)f2bf(x1.y); v1[2]=(short)f2bf(x1.z); v1[3]=(short)f2bf(x1.w);
      v1[4]=(short)f2bf(y1.x); v1[5]=(short)f2bf(y1.y); v1[6]=(short)f2bf(y1.z); v1[7]=(short)f2bf(y1.w);
      *(short8*)&Bs[(size_t)tid * 8] = v0;
      *(short8*)&Bs[(size_t)tid * 8 + 2048] = v1;
    }
    __syncthreads();
    short8 af[4], bfr[4];
#pragma unroll
    for (int x = 0; x < 4; ++x) {
      int ar = wm * 64 + x * 16 + (l & 15);
      af[x] = *(const short8*)&As[ar * 32 + ((l >> 4) << 3)];
      int br = wn * 64 + x * 16 + (l & 15);
      bfr[x] = *(const short8*)&Bs[br * 32 + ((l >> 4) << 3)];
    }
#pragma unroll
    for (int mf = 0; mf < 4; ++mf)
#pragma unroll
      for (int nf = 0; nf < 4; ++nf)
        acc[mf][nf] = mfma16(af[mf], bfr[nf], acc[mf][nf]);
    __syncthreads();
  }

  if constexpr (EPI == 2) {
    u16* C = (u16*)Cout;
#pragma unroll
    for (int mf = 0; mf < 4; ++mf) {
      int rbase = m0 + wm * 64 + mf * 16 + ((l >> 4) << 2);
      float bvr[4];
#pragma unroll
      for (int j = 0; j < 4; ++j) bvr[j] = bias[rbase + j];
#pragma unroll
      for (int nf = 0; nf < 4; ++nf) {
        int cg = n0 + wn * 64 + nf * 16 + (l & 15);
#pragma unroll
        for (int j = 0; j < 4; ++j)
          C[(size_t)(rbase + j) * ldc + cg] = f2bf_hw(acc[mf][nf][j] + bvr[j]);
      }
    }
  } else if constexpr (EPI == 3) {
    // ---- bf16 logits: LDS-staged, lane-contiguous short8 stores ----
    u16* C = (u16*)Cout;
    float* ep = epi + wid * 1024;               // [16][64] f32 per wave
    const int lq4 = l >> 4, l15e = l & 15;
    float bv[4];
#pragma unroll
    for (int nf = 0; nf < 4; ++nf) {
      int cg = n0 + wn * 64 + nf * 16 + l15e;
      bv[nf] = (cg < N) ? bias[cg] : 0.f;
    }
    const int r8 = l >> 3, c8 = l & 7;
    const int colb8 = n0 + wn * 64 + c8 * 8;
#pragma unroll
    for (int mf = 0; mf < 4; ++mf) {
#pragma unroll
      for (int nf = 0; nf < 4; ++nf)
#pragma unroll
        for (int j = 0; j < 4; ++j)
          ep[(lq4 * 4 + j) * 64 + nf * 16 + l15e] = acc[mf][nf][j] + bv[nf];
      asm volatile("s_waitcnt lgkmcnt(0)" ::: "memory");
      __builtin_amdgcn_sched_barrier(0);
#pragma unroll
      for (int pass = 0; pass < 2; ++pass) {
        const int rr = pass * 8 + r8;
        f32x4 v0 = *(const f32x4*)&ep[rr * 64 + c8 * 8];
        f32x4 v1 = *(const f32x4*)&ep[rr * 64 + c8 * 8 + 4];
        const int row = m0 + wm * 64 + mf * 16 + rr;
        const int orow = TMAJ ? ((row & 31) * TSZ + (row >> 5)) : row;
        float e = 0.f;
        if (colb8 + 7 < N) {
          short8 o;
          o[0]=(short)f2bf_hw(v0[0]); o[1]=(short)f2bf_hw(v0[1]);
          o[2]=(short)f2bf_hw(v0[2]); o[3]=(short)f2bf_hw(v0[3]);
          o[4]=(short)f2bf_hw(v1[0]); o[5]=(short)f2bf_hw(v1[1]);
          o[6]=(short)f2bf_hw(v1[2]); o[7]=(short)f2bf_hw(v1[3]);
          *(short8*)&C[(size_t)orow * ldc + colb8] = o;
          e = __expf(v0[0]) + __expf(v0[1]) + __expf(v0[2]) + __expf(v0[3]) +
              __expf(v1[0]) + __expf(v1[1]) + __expf(v1[2]) + __expf(v1[3]);
        } else {
#pragma unroll
          for (int kk = 0; kk < 8; ++kk) {
            float fv = (kk < 4) ? v0[kk] : v1[kk - 4];
            if (colb8 + kk < N) {
              C[(size_t)orow * ldc + colb8 + kk] = f2bf_hw(fv);
              e += __expf(fv);
            }
          }
        }
        e += __shfl_xor(e, 1, 8); e += __shfl_xor(e, 2, 8); e += __shfl_xor(e, 4, 8);
        if (c8 == 0) atomicAdd(&rowsum[orow], e);
      }
      asm volatile("s_waitcnt lgkmcnt(0)" ::: "memory");
      __builtin_amdgcn_sched_barrier(0);
    }
  } else {
    // ---- EPI 1: f32 direct, LDS-staged full-line f32x4 stores ----
    float* C = (float*)Cout;
    float* ep = epi + wid * 1024;
    const int lq4 = l >> 4, l15e = l & 15;
    float bv[4];
#pragma unroll
    for (int nf = 0; nf < 4; ++nf) {
      int cg = n0 + wn * 64 + nf * 16 + l15e;
      bv[nf] = (cg < N) ? bias[cg] : 0.f;
    }
    const int colbase = n0 + wn * 64 + l15e * 4;
#pragma unroll
    for (int mf = 0; mf < 4; ++mf) {
#pragma unroll
      for (int nf = 0; nf < 4; ++nf)
#pragma unroll
        for (int j = 0; j < 4; ++j)
          ep[(lq4 * 4 + j) * 64 + nf * 16 + l15e] = acc[mf][nf][j] + bv[nf];
      asm volatile("s_waitcnt lgkmcnt(0)" ::: "memory");
      __builtin_amdgcn_sched_barrier(0);
#pragma unroll
      for (int pass = 0; pass < 4; ++pass) {
        const int rr = pass * 4 + lq4;
        f32x4 v = *(const f32x4*)&ep[rr * 64 + l15e * 4];
        const int row = m0 + wm * 64 + mf * 16 + rr;
        const int orow = TMAJ ? ((row & 31) * TSZ + (row >> 5)) : row;
        float e = 0.f;
        if (colbase + 3 < N) {
          *(f32x4*)&C[(size_t)orow * ldc + colbase] = v;
          e = __expf(v[0]) + __expf(v[1]) + __expf(v[2]) + __expf(v[3]);
        } else {
#pragma unroll
          for (int kk = 0; kk < 4; ++kk)
            if (colbase + kk < N) {
              C[(size_t)orow * ldc + colbase + kk] = v[kk];
              e += __expf(v[kk]);
            }
        }
        e += __shfl_xor(e, 1, 16); e += __shfl_xor(e, 2, 16);
        e += __shfl_xor(e, 4, 16); e += __shfl_xor(e, 8, 16);
        if (l15e == 0) atomicAdd(&rowsum[orow], e);
      }
      asm volatile("s_waitcnt lgkmcnt(0)" ::: "memory");
      __builtin_amdgcn_sched_barrier(0);
    }
  }
}

// MAP 0: wg%nm / wg/nm grid (G0T). MAP 2: linear w = wofs + swizzled id (proj tiles).
template <int EPI, bool BCVT, int MAP, bool TMAJ>
__global__ __launch_bounds__(256) void gemm_bt(const u16* __restrict__ A,
                                               const void* __restrict__ Bsrc,
                                               void* __restrict__ Cout,
                                               const float* __restrict__ bias,
                                               float* __restrict__ rowsum,
                                               int nm, int nn, int N, int K, int ldc,
                                               int wofs) {
  __shared__ char smemg[16384];
  const int id = blockIdx.x;
  int bm, bn;
  if constexpr (MAP == 2) {
    const int gsz = (int)gridDim.x;
    int wg = ((gsz & 7) == 0) ? (id % 8) * (gsz >> 3) + (id >> 3) : id;
    int w = wofs + wg;
    bm = w / nn; bn = w % nn;
  } else {
    const int gsz = nm * nn;
    int wg = ((gsz & 7) == 0) ? (id % 8) * (gsz >> 3) + (id >> 3) : id;
    bm = wg % nm; bn = wg / nm;
  }
  gemm_tile<EPI, BCVT, TMAJ>(smemg, A, Bsrc, Cout, bias, rowsum,
                             bm * 128, bn * 128, N, K, ldc);
}

// ---------- cooperative kernel: LSTM workers + converter/early-proj blocks ----------
// bar: f0[0..63], f1[64..191], cvt-done[192..255].
struct LstmArgs {
  const u16* G0T;      // [4H, M4] bf16
  const float* Wih;    // [2,4H,H] f32
  const float* Whh;
  const float* bih, *bhh, *c0;
  u16* H0;             // [T+1, B, H]
  u16* H1;             // [T, B, H]  TIME-MAJOR
  const u16* h1init;   // [B, H]
  float* out_hc;
  unsigned* bar;
  const float* Wout;
  u16* Woutbf;
  u16* Lbf;            // bf16 logits (t-major tiles, out-row indexed)
  const float* bout;
  float* rowsum;
  int mode;            // 0 none, 1 cvt only, 2 cvt + early proj tiles
};

DEVI void stage_row_q(const float* src, char* row, int sw, int q) {
  for (int kk = 0; kk < 256; kk += 8) {
    float4 x = *(const float4*)(src + kk);
    float4 y = *(const float4*)(src + kk + 4);
    short8 v;
    v[0]=(short)f2bf(x.x); v[1]=(short)f2bf(x.y); v[2]=(short)f2bf(x.z); v[3]=(short)f2bf(x.w);
    v[4]=(short)f2bf(y.x); v[5]=(short)f2bf(y.y); v[6]=(short)f2bf(y.z); v[7]=(short)f2bf(y.w);
    const int kbyte = (q * 256 + kk) * 2;
    *(short8*)(row + (kbyte ^ sw)) = v;
  }
}

DEVI short8 ldsB(const char* lds, int r, int kbyte) {
  return *(const short8*)(lds + (size_t)r * 2048 + (kbyte ^ ((r & 7) << 4)));
}

DEVI void part_wr(float* part, int wstride_log2, int wv, int R, int lq, f32x4 v) {
  *(f32x4*)&part[(wv << wstride_log2) + (R << 4) + ((lq ^ (R & 3)) << 2)] = v;
}
DEVI float part_rd(const float* part, int wstride_log2, int wv, int R, int c) {
  return part[(wv << wstride_log2) + (R << 4) + ((((c >> 2) ^ (R & 3)) << 2)) + (c & 3)];
}

__global__ __launch_bounds__(256, 1) void lstm_coop(LstmArgs A) {
  extern __shared__ char smem[];
  const int wg = blockIdx.x, tid = threadIdx.x;
  const int wv = tid >> 6, l = tid & 63;
  const int l15 = l & 15, lq = l >> 4;
  const int bh = wv >> 1, kh = wv & 1;

  if (wg < 64) {
    // ===== layer 0 (round-9 structure, unchanged) =====
    char* WL = smem;
    float* part = (float*)(smem + 131072);
    const int j0 = wg << 4;
    {
      const int R = tid >> 2, q = tid & 3;
      const int grow = ((R >> 4) << 10) + j0 + (R & 15);
      stage_row_q(A.Whh + (size_t)grow * HSZ + q * 256, WL + (size_t)R * 2048,
                  (R & 7) << 4, q);
    }
    const int uu = tid & 15, bb = tid >> 4;
    float cst[2];
    cst[0] = A.c0[(size_t)bb * HSZ + j0 + uu];
    cst[1] = A.c0[(size_t)(bb + 16) * HSZ + j0 + uu];
    __syncthreads();
    unsigned* myflag = A.bar + wg;

    for (int t = 0; t < TSZ; ++t) {
      float g0v[4][2];
      {
        const int col = t * 32;
#pragma unroll
        for (int g4 = 0; g4 < 4; ++g4) {
          const u16* gp = A.G0T + (size_t)((g4 << 10) + j0 + uu) * M4 + col;
          g0v[g4][0] = bf2f(gp[bb]);
          g0v[g4][1] = bf2f(gp[bb + 16]);
        }
      }
      if (t > 0) wait64(A.bar, (unsigned)t, l);
      const u16* hprev = A.H0 + (size_t)t * (BSZ * HSZ);
      const u16* hb = hprev + (size_t)(bh * 16 + l15) * HSZ + (kh << 9) + (lq << 3);
      short8 a[16];
      cohld16x16(hb, a);
      __builtin_amdgcn_sched_barrier(0);
      f32x4 acc[4];
      { f32x4 z = {0.f,0.f,0.f,0.f}; acc[0]=z; acc[1]=z; acc[2]=z; acc[3]=z; }
#pragma unroll
      for (int k = 0; k < 16; ++k) {
        const int kbyte = (((kh << 4) + k) << 6) + (lq << 4);
#pragma unroll
        for (int tr = 0; tr < 4; ++tr)
          acc[tr] = mfma16(a[k], ldsB(WL, (tr << 4) + l15, kbyte), acc[tr]);
      }
#pragma unroll
      for (int tr = 0; tr < 4; ++tr)
        part_wr(part, 10, wv, (tr << 4) + l15, lq, acc[tr]);
      __syncthreads();
      const bool last = (t == TSZ - 1);
      u16* hnext = A.H0 + (size_t)(t + 1) * (BSZ * HSZ);
      u16 hv[2];
#pragma unroll
      for (int pp = 0; pp < 2; ++pp) {
        const int b = bb + (pp << 4);
        float gi = g0v[0][pp], gf = g0v[1][pp], gg = g0v[2][pp], go = g0v[3][pp];
#pragma unroll
        for (int kh2 = 0; kh2 < 2; ++kh2) {
          const int w2 = (pp << 1) | kh2;
          gi += part_rd(part, 10, w2, uu, bb);
          gf += part_rd(part, 10, w2, 16 + uu, bb);
          gg += part_rd(part, 10, w2, 32 + uu, bb);
          go += part_rd(part, 10, w2, 48 + uu, bb);
        }
        float i_ = sigm(gi), f_ = sigm(gf), g_ = tanh_fast(gg), o_ = sigm(go);
        float c_ = f_ * cst[pp] + i_ * g_;
        cst[pp] = c_;
        float h_ = o_ * tanh_fast(c_);
        hv[pp] = f2bf(h_);
        if (last) {
          A.out_hc[(size_t)b * HSZ + j0 + uu] = h_;
          A.out_hc[2 * BSZ * HSZ + (size_t)b * HSZ + j0 + uu] = c_;
        }
      }
      cohst2_u16(hnext + (size_t)bb * HSZ + j0 + uu, hv[0],
                 hnext + (size_t)(bb + 16) * HSZ + j0 + uu, hv[1]);
      __syncthreads();
      if (tid == 0) flagst(myflag, (unsigned)(t + 1));
    }
  } else if (wg < NWRK) {
    // ===== layer 1 (round-9 structure; H1 now time-major) =====
    char* WxL = smem;
    char* WhL = smem + 65536;
    float* part = (float*)(smem + 131072);
    float* biasL = (float*)(smem + 139264);
    const int lw = wg - 64;
    const int j1 = lw << 3;
    {
      const int rr = tid >> 2, q = tid & 3;
      const int r = rr & 31;
      const int grow = FH + ((r >> 3) << 10) + j1 + (r & 7);
      const float* base = (rr >= 32) ? A.Whh : A.Wih;
      char* dst = ((rr >= 32) ? WhL : WxL) + (size_t)r * 2048;
      stage_row_q(base + (size_t)grow * HSZ + q * 256, dst, (r & 7) << 4, q);
    }
    if (tid < 32) {
      const int grow = FH + ((tid >> 3) << 10) + j1 + (tid & 7);
      biasL[tid] = A.bih[grow] + A.bhh[grow];
    }
    const int uu = tid & 7, b1 = tid >> 3;
    float cst = A.c0[BSZ * HSZ + (size_t)b1 * HSZ + j1 + uu];
    __syncthreads();
    unsigned* myflag = A.bar + 64 + lw;

    for (int t = 0; t < TSZ; ++t) {
      wait64(A.bar, (unsigned)(t + 1), l);
      const u16* x1 = A.H0 + (size_t)(t + 1) * (BSZ * HSZ);
      const u16* xb = x1 + (size_t)(bh * 16 + l15) * HSZ + (kh << 9) + (lq << 3);
      short8 ax[16];
      cohld16x16(xb, ax);
      __builtin_amdgcn_sched_barrier(0);
      f32x4 acc[2];
      { f32x4 z = {0.f,0.f,0.f,0.f}; acc[0]=z; acc[1]=z; }
#pragma unroll
      for (int k = 0; k < 16; ++k) {
        const int kbyte = (((kh << 4) + k) << 6) + (lq << 4);
        acc[0] = mfma16(ax[k], ldsB(WxL, l15, kbyte), acc[0]);
        acc[1] = mfma16(ax[k], ldsB(WxL, 16 + l15, kbyte), acc[1]);
      }
      if (t > 0) wait128(A.bar + 64, (unsigned)t, l);
      const u16* hp = (t == 0) ? A.h1init : A.H1 + (size_t)(t - 1) * (BSZ * HSZ);
      const u16* hbp = hp + (size_t)(bh * 16 + l15) * HSZ + (kh << 9) + (lq << 3);
      short8 ah[16];
      cohld16x16(hbp, ah);
      __builtin_amdgcn_sched_barrier(0);
#pragma unroll
      for (int k = 0; k < 16; ++k) {
        const int kbyte = (((kh << 4) + k) << 6) + (lq << 4);
        acc[0] = mfma16(ah[k], ldsB(WhL, l15, kbyte), acc[0]);
        acc[1] = mfma16(ah[k], ldsB(WhL, 16 + l15, kbyte), acc[1]);
      }
#pragma unroll
      for (int tr = 0; tr < 2; ++tr)
        part_wr(part, 9, wv, (tr << 4) + l15, lq, acc[tr]);
      __syncthreads();
      const bool last = (t == TSZ - 1);
      {
        const int c = b1 & 15, ph = b1 >> 4;
        float gi = biasL[uu], gf = biasL[8 + uu], gg = biasL[16 + uu], go = biasL[24 + uu];
#pragma unroll
        for (int kh2 = 0; kh2 < 2; ++kh2) {
          const int w2 = (ph << 1) | kh2;
          gi += part_rd(part, 9, w2, uu, c);
          gf += part_rd(part, 9, w2, 8 + uu, c);
          gg += part_rd(part, 9, w2, 16 + uu, c);
          go += part_rd(part, 9, w2, 24 + uu, c);
        }
        float i_ = sigm(gi), f_ = sigm(gf), g_ = tanh_fast(gg), o_ = sigm(go);
        float c_ = f_ * cst + i_ * g_;
        cst = c_;
        float h_ = o_ * tanh_fast(c_);
        cohst1_u16(A.H1 + (size_t)t * (BSZ * HSZ) + (size_t)b1 * HSZ + j1 + uu, f2bf(h_));
        if (last) {
          A.out_hc[BSZ * HSZ + (size_t)b1 * HSZ + j1 + uu] = h_;
          A.out_hc[3 * BSZ * HSZ + (size_t)b1 * HSZ + j1 + uu] = c_;
        }
      }
      __syncthreads();
      if (tid == 0) flagst(myflag, (unsigned)(t + 1));
    }
  } else {
    // ===== converter + early-proj blocks =====
    const int cid = wg - NWRK;     // 0..63
    if (A.mode >= 1) {
      const int n4 = (int)((size_t)VSZ * HSZ / 4);
      const float4* src = (const float4*)A.Wout;
      ushort4* dst = (ushort4*)A.Woutbf;
      for (int i = cid * 256 + tid; i < n4; i += 64 * 256) {
        float4 v = src[i];
        ushort4 o;
        o.x = f2bf_hw(v.x); o.y = f2bf_hw(v.y); o.z = f2bf_hw(v.z); o.w = f2bf_hw(v.w);
        dst[i] = o;
      }
      // make this block's Woutbf writes LLC-visible (cross-XCD readers in-kernel)
      asm volatile("s_waitcnt vmcnt(0)" ::: "memory");
      __builtin_amdgcn_fence(__ATOMIC_RELEASE, "agent");
      __syncthreads();
      if (tid == 0) flagst(A.bar + 192 + cid, 1u);
      if (A.mode == 2) {
        wait64(A.bar + 192, 1u, l);   // all converters done
        __syncthreads();
        for (int k = 0; k < CVT_PER; ++k) {
          const int w = cid + (k << 6);          // bm-ascending across blocks
          const int bm = w / NNT, bn = w % NNT;
          wait128(A.bar + 64, (unsigned)(4 * bm + 4), l);
          __syncthreads();
          gemm_tile<3, false, true>(smem, A.H1, A.Woutbf, A.Lbf, A.bout, A.rowsum,
                                    bm * 128, bn * 128, VSZ, HSZ, LDBF);
        }
      }
    }
  }
}

// ---------- logsumexp finish ----------
__global__ void lse_kernel(float* __restrict__ rowsum, int n) {
  int i = blockIdx.x * 256 + threadIdx.x;
  if (i < n) rowsum[i] = logf(rowsum[i]);
}

__global__ __launch_bounds__(256) void lsm_finish(float* __restrict__ C,
                                                  const float* __restrict__ lse, int Vd) {
  int row = blockIdx.y;
  size_t start = (size_t)row * (size_t)Vd;
  float s = lse[row];
  int i = blockIdx.x * 256 + threadIdx.x;
  int col = i * 4;
  if (col + 3 < Vd) {
    f32x4* p = (f32x4*)(C + start + col);
    f32x4 v = *p;
    v[0] -= s; v[1] -= s; v[2] -= s; v[3] -= s;
    *p = v;
  } else {
    for (int j = col; j < Vd; ++j) C[start + j] -= s;
  }
}

__global__ __launch_bounds__(256) void lsm_finish_bf(const u16* __restrict__ L,
                                                     float* __restrict__ out,
                                                     const float* __restrict__ rowsum,
                                                     int Vd, int ldl) {
  int row = blockIdx.y;
  float s = logf(rowsum[row]);
  int col = blockIdx.x * 2048 + threadIdx.x * 8;
  const u16* lp = L + (size_t)row * ldl;
  float* op = out + (size_t)row * Vd;
  if (col + 7 < Vd) {
    short8 v = *(const short8*)(lp + col);
    f32x4 a, b;
    a[0] = bf2f((u16)v[0]) - s; a[1] = bf2f((u16)v[1]) - s;
    a[2] = bf2f((u16)v[2]) - s; a[3] = bf2f((u16)v[3]) - s;
    b[0] = bf2f((u16)v[4]) - s; b[1] = bf2f((u16)v[5]) - s;
    b[2] = bf2f((u16)v[6]) - s; b[3] = bf2f((u16)v[7]) - s;
    *(f32x4*)(op + col) = a;
    *(f32x4*)(op + col + 4) = b;
  } else {
    for (int j = col; j < Vd; ++j) op[j] = bf2f(lp[j]) - s;
  }
}

// ---------- launcher ----------
extern "C" void kernel_launch(void* const* d_in, const int* in_sizes, int n_in,
                              void* d_out, int out_size, void* d_ws, size_t ws_size,
                              hipStream_t stream) {
  const int* tokens = (const int*)d_in[0];
  const float* emb = (const float*)d_in[1];
  const float* Wih = (const float*)d_in[2];
  const float* Whh = (const float*)d_in[3];
  const float* bih = (const float*)d_in[4];
  const float* bhh = (const float*)d_in[5];
  const float* Wout = (const float*)d_in[6];
  const float* bout = (const float*)d_in[7];
  const float* h0 = (const float*)d_in[8];
  const float* c0 = (const float*)d_in[9];
  float* out = (float*)d_out;

  char* w = (char*)d_ws;
  size_t o = 0;
  u16* Xbf = (u16*)(w + o);    o += (size_t)M4 * HSZ * 2;
  u16* Wih0bf = (u16*)(w + o); o += (size_t)FH * HSZ * 2;
  u16* G0T = (u16*)(w + o);    o += (size_t)FH * M4 * 2;
  u16* H0 = (u16*)(w + o);     o += (size_t)(TSZ + 1) * BSZ * HSZ * 2;
  u16* H1 = (u16*)(w + o);     o += (size_t)BSZ * TSZ * HSZ * 2;
  u16* h1init = (u16*)(w + o); o += (size_t)BSZ * HSZ * 2;
  float* bias0 = (float*)(w + o);  o += FH * 4;
  float* rowsum = (float*)(w + o); o += M4 * 4;
  unsigned* bar = (unsigned*)(w + o); o += 4096;
  u16* Woutbf = (u16*)(w + o);
  size_t need_full = o + (size_t)VSZ * HSZ * 2;
  u16* Lbf = (u16*)(w + need_full);
  size_t need_lbf = need_full + (size_t)M4 * LDBF * 2;
  const bool bcvt = (ws_size < need_full);
  const bool bf16c = (ws_size >= need_lbf);
  const int mode = bcvt ? 0 : (bf16c ? 2 : 1);

  prep_all<<<128, 256, 0, stream>>>(bih, bhh, bias0, rowsum, bar, h0, H0, h1init);
  cvt_bf16<<<2048, 256, 0, stream>>>(Wih, Wih0bf, FH * HSZ / 4);
  embed_kernel<<<M4, 256, 0, stream>>>(tokens, emb, Xbf);
  // G0T[4H][M4] = Wih0 @ X^T + (b_ih0 + b_hh0)
  gemm_bt<2, false, 0, false><<<32 * 32, 256, 0, stream>>>(
      Wih0bf, Xbf, G0T, bias0, nullptr, 32, 32, M4, HSZ, M4, 0);

  LstmArgs la{G0T, Wih, Whh, bih, bhh, c0, H0, H1, h1init,
              out + (size_t)OUT_LOGP, bar, Wout, Woutbf, Lbf, bout, rowsum, mode};
  void* kargs[] = {&la};
  hipFuncSetAttribute((const void*)lstm_coop, hipFuncAttributeMaxDynamicSharedMemorySize, LDSB);
  hipLaunchCooperativeKernel((const void*)lstm_coop, dim3(NBLK), dim3(256), kargs, LDSB, stream);

  const int TOT = 32 * NNT;   // 12576 proj tiles
  if (bf16c) {
    gemm_bt<3, false, 2, true><<<TOT - CVTILES, 256, 0, stream>>>(
        H1, Woutbf, Lbf, bout, rowsum, 32, NNT, VSZ, HSZ, LDBF, CVTILES);
    lsm_finish_bf<<<dim3(25, M4), 256, 0, stream>>>(Lbf, out, rowsum, VSZ, LDBF);
  } else if (!bcvt) {
    gemm_bt<1, false, 2, true><<<TOT, 256, 0, stream>>>(
        H1, Woutbf, out, bout, rowsum, 32, NNT, VSZ, HSZ, VSZ, 0);
    lse_kernel<<<16, 256, 0, stream>>>(rowsum, M4);
    lsm_finish<<<dim3((VSZ + 1023) / 1024, M4), 256, 0, stream>>>(out, rowsum, VSZ);
  } else {
    gemm_bt<1, true, 2, true><<<TOT, 256, 0, stream>>>(
        H1, Wout, out, bout, rowsum, 32, NNT, VSZ, HSZ, VSZ, 0);
    lse_kernel<<<16, 256, 0, stream>>>(rowsum, M4);
    lsm_finish<<<dim3((VSZ + 1023) / 1024, M4), 256, 0, stream>>>(out, rowsum, VSZ);
  }
}

// Round 15
// 1662.595 us; speedup vs baseline: 1.0610x; 1.0610x over previous
//
#include <hip/hip_runtime.h>
#include <hip/hip_bf16.h>
#include <cstdint>
#include <cstddef>

#define DEVI __device__ __forceinline__

typedef __attribute__((ext_vector_type(8))) short short8;
typedef __attribute__((ext_vector_type(4))) float f32x4;
using u16 = unsigned short;

constexpr int BSZ = 32, TSZ = 128, VSZ = 50257, HSZ = 1024;
constexpr int M4 = BSZ * TSZ;          // 4096 rows
constexpr int FH = 4 * HSZ;            // 4096 gate rows
constexpr long long OUT_LOGP = (long long)M4 * VSZ;
constexpr int NWRK = 192;              // 64 layer0 + 128 layer1 worker blocks
constexpr int NBLK = 256;              // + 64 converter/early-proj blocks
constexpr int LDSB = 147584;           // dynamic LDS bytes (lstm)
constexpr int LDBF = 50258;            // bf16 logit row stride
constexpr int NNT = 393;               // proj n-tiles
constexpr int CVT_PER = 12;            // early proj tiles per converter block
constexpr int CVTILES = 64 * CVT_PER;  // 768 tiles done inside coop

// ---------- small helpers ----------
DEVI u16 f2bf(float f) {
  unsigned u = __float_as_uint(f);
  unsigned r = (u + 0x7fffu + ((u >> 16) & 1u)) >> 16;
  return (u16)r;
}
DEVI u16 f2bf_hw(float f) {
  __hip_bfloat16 h = __float2bfloat16(f);
  return __builtin_bit_cast(u16, h);
}
DEVI float bf2f(u16 u) { return __uint_as_float(((unsigned)u) << 16); }
DEVI float sigm(float x) { return 1.f / (1.f + __expf(-x)); }
DEVI float tanh_fast(float x) { return 1.f - 2.f / (1.f + __expf(2.f * x)); }

DEVI f32x4 mfma16(short8 a, short8 b, f32x4 c) {
  return __builtin_amdgcn_mfma_f32_16x16x32_bf16(a, b, c, 0, 0, 0);
}

DEVI void gld16(const void* g, void* l) {
  auto gp = (const __attribute__((address_space(1))) unsigned int*)g;
  auto lp = (__attribute__((address_space(3))) unsigned int*)l;
  __builtin_amdgcn_global_load_lds(gp, lp, 16, 0, 0);
}

// ---------- SAFE coherent primitives ----------
DEVI void cohld16x16(const u16* base, short8 (&d)[16]) {
  asm volatile(
      "global_load_dwordx4 %0, %16, off sc0 sc1\n\t"
      "global_load_dwordx4 %1, %16, off offset:64 sc0 sc1\n\t"
      "global_load_dwordx4 %2, %16, off offset:128 sc0 sc1\n\t"
      "global_load_dwordx4 %3, %16, off offset:192 sc0 sc1\n\t"
      "global_load_dwordx4 %4, %16, off offset:256 sc0 sc1\n\t"
      "global_load_dwordx4 %5, %16, off offset:320 sc0 sc1\n\t"
      "global_load_dwordx4 %6, %16, off offset:384 sc0 sc1\n\t"
      "global_load_dwordx4 %7, %16, off offset:448 sc0 sc1\n\t"
      "global_load_dwordx4 %8, %16, off offset:512 sc0 sc1\n\t"
      "global_load_dwordx4 %9, %16, off offset:576 sc0 sc1\n\t"
      "global_load_dwordx4 %10, %16, off offset:640 sc0 sc1\n\t"
      "global_load_dwordx4 %11, %16, off offset:704 sc0 sc1\n\t"
      "global_load_dwordx4 %12, %16, off offset:768 sc0 sc1\n\t"
      "global_load_dwordx4 %13, %16, off offset:832 sc0 sc1\n\t"
      "global_load_dwordx4 %14, %16, off offset:896 sc0 sc1\n\t"
      "global_load_dwordx4 %15, %16, off offset:960 sc0 sc1\n\t"
      "s_waitcnt vmcnt(0)"
      : "=&v"(d[0]), "=&v"(d[1]), "=&v"(d[2]), "=&v"(d[3]),
        "=&v"(d[4]), "=&v"(d[5]), "=&v"(d[6]), "=&v"(d[7]),
        "=&v"(d[8]), "=&v"(d[9]), "=&v"(d[10]), "=&v"(d[11]),
        "=&v"(d[12]), "=&v"(d[13]), "=&v"(d[14]), "=&v"(d[15])
      : "v"(base)
      : "memory");
}
DEVI void cohst2_u16(u16* p0, u16 v0, u16* p1, u16 v1) {
  asm volatile(
      "global_store_short %0, %2, off sc0 sc1\n\t"
      "global_store_short %1, %3, off sc0 sc1\n\t"
      "s_waitcnt vmcnt(0)"
      :: "v"(p0), "v"(p1), "v"((unsigned)v0), "v"((unsigned)v1)
      : "memory");
}
DEVI void cohst1_u16(u16* p0, u16 v0) {
  asm volatile(
      "global_store_short %0, %1, off sc0 sc1\n\t"
      "s_waitcnt vmcnt(0)"
      :: "v"(p0), "v"((unsigned)v0)
      : "memory");
}
DEVI void flagst(unsigned* p, unsigned v) {
  __hip_atomic_store(p, v, __ATOMIC_RELAXED, __HIP_MEMORY_SCOPE_AGENT);
}
DEVI unsigned flagld(const unsigned* p) {
  return __hip_atomic_load(p, __ATOMIC_RELAXED, __HIP_MEMORY_SCOPE_AGENT);
}

DEVI void wait64(const unsigned* f, unsigned g, int l) {
  while (!__all((int)(flagld(f + l) >= g))) __builtin_amdgcn_s_sleep(1);
}
DEVI void wait128(const unsigned* f, unsigned g, int l) {
  for (;;) {
    unsigned a = flagld(f + l);
    unsigned b = flagld(f + 64 + l);
    if (__all((int)((a >= g) && (b >= g)))) break;
    __builtin_amdgcn_s_sleep(1);
  }
}

// ---------- prep (merged) ----------
__global__ void prep_all(const float* __restrict__ bih, const float* __restrict__ bhh,
                         float* __restrict__ bias0, float* __restrict__ rowsum,
                         unsigned* __restrict__ bar, const float* __restrict__ h0,
                         u16* __restrict__ H0, u16* __restrict__ h1init) {
  int i = blockIdx.x * 256 + threadIdx.x;   // 0..32767
  H0[i] = f2bf(h0[i]);
  h1init[i] = f2bf(h0[BSZ * HSZ + i]);
  if (i < FH) { bias0[i] = bih[i] + bhh[i]; rowsum[i] = 0.f; }
  if (i < 1024) bar[i] = 0u;
}

__global__ void cvt_bf16(const float* __restrict__ src, u16* __restrict__ dst, int n4) {
  int i = blockIdx.x * blockDim.x + threadIdx.x;
  int stride = gridDim.x * blockDim.x;
  for (; i < n4; i += stride) {
    float4 v = ((const float4*)src)[i];
    ushort4 o; o.x = f2bf(v.x); o.y = f2bf(v.y); o.z = f2bf(v.z); o.w = f2bf(v.w);
    ((ushort4*)dst)[i] = o;
  }
}

__global__ __launch_bounds__(256) void embed_kernel(const int* __restrict__ tok,
                                                    const float* __restrict__ emb,
                                                    u16* __restrict__ X) {
  int m = blockIdx.x;                // m = t*32 + b
  int t = m >> 5, b = m & 31;
  int token = tok[b * TSZ + t];
  const float4* src = (const float4*)(emb + (size_t)token * HSZ);
  int i = threadIdx.x;
  float4 v = src[i];
  ushort4 o; o.x = f2bf(v.x); o.y = f2bf(v.y); o.z = f2bf(v.z); o.w = f2bf(v.w);
  *(ushort4*)(X + (size_t)m * HSZ + i * 4) = o;
}

// ---------- 128x128 bf16 MFMA GEMM tile, BK=64, XOR-swizzled LDS ----------
// LDS: As[128][64], Bs[128][64] bf16 (32KB). Stage via pre-swizzled GLOBAL source
// (rule #21: swizzle source AND read, LDS dst stays linear for global_load_lds).
// Element col ^= (row&7)*8 within each 64-elem row -> ds_read ~2-way conflicts.
// EPI 1: C f32 staged stores. EPI 2: C bf16 bias[row] (G0T). EPI 3: C bf16 staged.
// TMAJ: A rows t-major (t*32+b); C/rowsum remapped to out-row b*T+t.
template <int EPI, bool BCVT, bool TMAJ>
DEVI void gemm_tile(char* smemg, const u16* __restrict__ A, const void* __restrict__ Bsrc,
                    void* __restrict__ Cout, const float* __restrict__ bias,
                    float* __restrict__ rowsum, int m0, int n0, int N, int K, int ldc) {
  u16* As = (u16*)smemg;                 // [128][64]
  u16* Bs = (u16*)(smemg + 16384);       // [128][64]
  float* epi = (float*)smemg;            // [4 waves][16][64] f32 (epilogue alias)
  const int tid = threadIdx.x;
  const int l = tid & 63, wid = tid >> 6;
  const int wm = wid >> 1, wn = wid & 1;

  // staging geometry: per round, 256 threads cover 32 rows x 64 cols (16B/lane)
  const int srow8 = tid >> 3;                       // 0..31 (= wave*8 + (l>>3))
  const int scol = ((tid & 7) * 8) ^ ((srow8 & 7) << 3);  // swizzled element col
  u16* AsW = As + (size_t)(tid >> 6) * 8 * 64;      // wave-uniform base (8 rows)
  u16* BsW = Bs + (size_t)(tid >> 6) * 8 * 64;

  const u16* Bbf = (const u16*)Bsrc;
  const float* Bf32 = (const float*)Bsrc;

  f32x4 acc[4][4];
  f32x4 z = {0.f, 0.f, 0.f, 0.f};
#pragma unroll
  for (int a = 0; a < 4; ++a)
#pragma unroll
    for (int b = 0; b < 4; ++b) acc[a][b] = z;

  for (int k0 = 0; k0 < K; k0 += 64) {
#pragma unroll
    for (int rr = 0; rr < 4; ++rr) {
      gld16(A + (size_t)(m0 + rr * 32 + srow8) * K + k0 + scol, AsW + rr * 2048);
      if (!BCVT) {
        int br = n0 + rr * 32 + srow8; if (br > N - 1) br = N - 1;
        gld16(Bbf + (size_t)br * K + k0 + scol, BsW + rr * 2048);
      }
    }
    if (BCVT) {
#pragma unroll
      for (int half = 0; half < 2; ++half) {
        const int row = half * 64 + (tid >> 2);
        int br = n0 + row; if (br > N - 1) br = N - 1;
        const int c0 = (tid & 3) * 16;
        const float* s = Bf32 + (size_t)br * K + k0 + c0;
        const int sw = (row & 7) << 3;
        float4 x0 = *(const float4*)s,       y0 = *(const float4*)(s + 4);
        float4 x1 = *(const float4*)(s + 8), y1 = *(const float4*)(s + 12);
        short8 v0, v1;
        v0[0]=(short)f2bf(x0.x); v0[1]=(short)f2bf(x0.y); v0[2]=(short)f2bf(x0.z); v0[3]=(short)f2bf(x0.w);
        v0[4]=(short)f2bf(y0.x); v0[5]=(short)f2bf(y0.y); v0[6]=(short)f2bf(y0.z); v0[7]=(short)f2bf(y0.w);
        v1[0]=(short)f2bf(x1.x); v1[1]=(short)f2bf(x1.y); v1[2]=(short)f2bf(x1.z); v1[3]=(short)f2bf(x1.w);
        v1[4]=(short)f2bf(y1.x); v1[5]=(short)f2bf(y1.y); v1[6]=(short)f2bf(y1.z); v1[7]=(short)f2bf(y1.w);
        *(short8*)&Bs[row * 64 + (c0 ^ sw)] = v0;
        *(short8*)&Bs[row * 64 + ((c0 + 8) ^ sw)] = v1;
      }
    }
    __syncthreads();
#pragma unroll
    for (int ks = 0; ks < 2; ++ks) {
      short8 af[4], bfr[4];
#pragma unroll
      for (int x = 0; x < 4; ++x) {
        const int ar = wm * 64 + x * 16 + (l & 15);
        const int ka = (ks * 64 + (l >> 4) * 16) ^ ((ar & 7) << 4);
        af[x] = *(const short8*)((const char*)As + ar * 128 + ka);
        const int br = wn * 64 + x * 16 + (l & 15);
        const int kb = (ks * 64 + (l >> 4) * 16) ^ ((br & 7) << 4);
        bfr[x] = *(const short8*)((const char*)Bs + br * 128 + kb);
      }
#pragma unroll
      for (int mf = 0; mf < 4; ++mf)
#pragma unroll
        for (int nf = 0; nf < 4; ++nf)
          acc[mf][nf] = mfma16(af[mf], bfr[nf], acc[mf][nf]);
    }
    __syncthreads();
  }

  if constexpr (EPI == 2) {
    u16* C = (u16*)Cout;
#pragma unroll
    for (int mf = 0; mf < 4; ++mf) {
      int rbase = m0 + wm * 64 + mf * 16 + ((l >> 4) << 2);
      float bvr[4];
#pragma unroll
      for (int j = 0; j < 4; ++j) bvr[j] = bias[rbase + j];
#pragma unroll
      for (int nf = 0; nf < 4; ++nf) {
        int cg = n0 + wn * 64 + nf * 16 + (l & 15);
#pragma unroll
        for (int j = 0; j < 4; ++j)
          C[(size_t)(rbase + j) * ldc + cg] = f2bf_hw(acc[mf][nf][j] + bvr[j]);
      }
    }
  } else if constexpr (EPI == 3) {
    u16* C = (u16*)Cout;
    float* ep = epi + wid * 1024;
    const int lq4 = l >> 4, l15e = l & 15;
    float bv[4];
#pragma unroll
    for (int nf = 0; nf < 4; ++nf) {
      int cg = n0 + wn * 64 + nf * 16 + l15e;
      bv[nf] = (cg < N) ? bias[cg] : 0.f;
    }
    const int r8 = l >> 3, c8 = l & 7;
    const int colb8 = n0 + wn * 64 + c8 * 8;
#pragma unroll
    for (int mf = 0; mf < 4; ++mf) {
#pragma unroll
      for (int nf = 0; nf < 4; ++nf)
#pragma unroll
        for (int j = 0; j < 4; ++j)
          ep[(lq4 * 4 + j) * 64 + nf * 16 + l15e] = acc[mf][nf][j] + bv[nf];
      asm volatile("s_waitcnt lgkmcnt(0)" ::: "memory");
      __builtin_amdgcn_sched_barrier(0);
#pragma unroll
      for (int pass = 0; pass < 2; ++pass) {
        const int rr = pass * 8 + r8;
        f32x4 v0 = *(const f32x4*)&ep[rr * 64 + c8 * 8];
        f32x4 v1 = *(const f32x4*)&ep[rr * 64 + c8 * 8 + 4];
        const int row = m0 + wm * 64 + mf * 16 + rr;
        const int orow = TMAJ ? ((row & 31) * TSZ + (row >> 5)) : row;
        float e = 0.f;
        if (colb8 + 7 < N) {
          short8 o;
          o[0]=(short)f2bf_hw(v0[0]); o[1]=(short)f2bf_hw(v0[1]);
          o[2]=(short)f2bf_hw(v0[2]); o[3]=(short)f2bf_hw(v0[3]);
          o[4]=(short)f2bf_hw(v1[0]); o[5]=(short)f2bf_hw(v1[1]);
          o[6]=(short)f2bf_hw(v1[2]); o[7]=(short)f2bf_hw(v1[3]);
          *(short8*)&C[(size_t)orow * ldc + colb8] = o;
          e = __expf(v0[0]) + __expf(v0[1]) + __expf(v0[2]) + __expf(v0[3]) +
              __expf(v1[0]) + __expf(v1[1]) + __expf(v1[2]) + __expf(v1[3]);
        } else {
#pragma unroll
          for (int kk = 0; kk < 8; ++kk) {
            float fv = (kk < 4) ? v0[kk] : v1[kk - 4];
            if (colb8 + kk < N) {
              C[(size_t)orow * ldc + colb8 + kk] = f2bf_hw(fv);
              e += __expf(fv);
            }
          }
        }
        e += __shfl_xor(e, 1, 8); e += __shfl_xor(e, 2, 8); e += __shfl_xor(e, 4, 8);
        if (c8 == 0) atomicAdd(&rowsum[orow], e);
      }
      asm volatile("s_waitcnt lgkmcnt(0)" ::: "memory");
      __builtin_amdgcn_sched_barrier(0);
    }
  } else {
    float* C = (float*)Cout;
    float* ep = epi + wid * 1024;
    const int lq4 = l >> 4, l15e = l & 15;
    float bv[4];
#pragma unroll
    for (int nf = 0; nf < 4; ++nf) {
      int cg = n0 + wn * 64 + nf * 16 + l15e;
      bv[nf] = (cg < N) ? bias[cg] : 0.f;
    }
    const int colbase = n0 + wn * 64 + l15e * 4;
#pragma unroll
    for (int mf = 0; mf < 4; ++mf) {
#pragma unroll
      for (int nf = 0; nf < 4; ++nf)
#pragma unroll
        for (int j = 0; j < 4; ++j)
          ep[(lq4 * 4 + j) * 64 + nf * 16 + l15e] = acc[mf][nf][j] + bv[nf];
      asm volatile("s_waitcnt lgkmcnt(0)" ::: "memory");
      __builtin_amdgcn_sched_barrier(0);
#pragma unroll
      for (int pass = 0; pass < 4; ++pass) {
        const int rr = pass * 4 + lq4;
        f32x4 v = *(const f32x4*)&ep[rr * 64 + l15e * 4];
        const int row = m0 + wm * 64 + mf * 16 + rr;
        const int orow = TMAJ ? ((row & 31) * TSZ + (row >> 5)) : row;
        float e = 0.f;
        if (colbase + 3 < N) {
          *(f32x4*)&C[(size_t)orow * ldc + colbase] = v;
          e = __expf(v[0]) + __expf(v[1]) + __expf(v[2]) + __expf(v[3]);
        } else {
#pragma unroll
          for (int kk = 0; kk < 4; ++kk)
            if (colbase + kk < N) {
              C[(size_t)orow * ldc + colbase + kk] = v[kk];
              e += __expf(v[kk]);
            }
        }
        e += __shfl_xor(e, 1, 16); e += __shfl_xor(e, 2, 16);
        e += __shfl_xor(e, 4, 16); e += __shfl_xor(e, 8, 16);
        if (l15e == 0) atomicAdd(&rowsum[orow], e);
      }
      asm volatile("s_waitcnt lgkmcnt(0)" ::: "memory");
      __builtin_amdgcn_sched_barrier(0);
    }
  }
}

// MAP 0: wg%nm / wg/nm grid (G0T). MAP 2: linear w = wofs + swizzled id (proj tiles).
template <int EPI, bool BCVT, int MAP, bool TMAJ>
__global__ __launch_bounds__(256) void gemm_bt(const u16* __restrict__ A,
                                               const void* __restrict__ Bsrc,
                                               void* __restrict__ Cout,
                                               const float* __restrict__ bias,
                                               float* __restrict__ rowsum,
                                               int nm, int nn, int N, int K, int ldc,
                                               int wofs) {
  __shared__ char smemg[32768];
  const int id = blockIdx.x;
  int bm, bn;
  if constexpr (MAP == 2) {
    const int gsz = (int)gridDim.x;
    int wg = ((gsz & 7) == 0) ? (id % 8) * (gsz >> 3) + (id >> 3) : id;
    int w = wofs + wg;
    bm = w / nn; bn = w % nn;
  } else {
    const int gsz = nm * nn;
    int wg = ((gsz & 7) == 0) ? (id % 8) * (gsz >> 3) + (id >> 3) : id;
    bm = wg % nm; bn = wg / nm;
  }
  gemm_tile<EPI, BCVT, TMAJ>(smemg, A, Bsrc, Cout, bias, rowsum,
                             bm * 128, bn * 128, N, K, ldc);
}

// ---------- cooperative kernel: LSTM workers + converter/early-proj blocks ----------
struct LstmArgs {
  const u16* G0T;      // [4H, M4] bf16
  const float* Wih;    // [2,4H,H] f32
  const float* Whh;
  const float* bih, *bhh, *c0;
  u16* H0;             // [T+1, B, H]
  u16* H1;             // [T, B, H]  TIME-MAJOR
  const u16* h1init;   // [B, H]
  float* out_hc;
  unsigned* bar;       // f0[0..63], f1[64..191], cvt-done[192..255]
  const float* Wout;
  u16* Woutbf;
  u16* Lbf;
  const float* bout;
  float* rowsum;
  int mode;            // 0 none, 1 cvt only, 2 cvt + early proj tiles
};

DEVI void stage_row_q(const float* src, char* row, int sw, int q) {
  for (int kk = 0; kk < 256; kk += 8) {
    float4 x = *(const float4*)(src + kk);
    float4 y = *(const float4*)(src + kk + 4);
    short8 v;
    v[0]=(short)f2bf(x.x); v[1]=(short)f2bf(x.y); v[2]=(short)f2bf(x.z); v[3]=(short)f2bf(x.w);
    v[4]=(short)f2bf(y.x); v[5]=(short)f2bf(y.y); v[6]=(short)f2bf(y.z); v[7]=(short)f2bf(y.w);
    const int kbyte = (q * 256 + kk) * 2;
    *(short8*)(row + (kbyte ^ sw)) = v;
  }
}

DEVI short8 ldsB(const char* lds, int r, int kbyte) {
  return *(const short8*)(lds + (size_t)r * 2048 + (kbyte ^ ((r & 7) << 4)));
}

DEVI void part_wr(float* part, int wstride_log2, int wv, int R, int lq, f32x4 v) {
  *(f32x4*)&part[(wv << wstride_log2) + (R << 4) + ((lq ^ (R & 3)) << 2)] = v;
}
DEVI float part_rd(const float* part, int wstride_log2, int wv, int R, int c) {
  return part[(wv << wstride_log2) + (R << 4) + ((((c >> 2) ^ (R & 3)) << 2)) + (c & 3)];
}

__global__ __launch_bounds__(256, 1) void lstm_coop(LstmArgs A) {
  extern __shared__ char smem[];
  const int wg = blockIdx.x, tid = threadIdx.x;
  const int wv = tid >> 6, l = tid & 63;
  const int l15 = l & 15, lq = l >> 4;
  const int bh = wv >> 1, kh = wv & 1;

  if (wg < 64) {
    // ===== layer 0 (round-9 structure) =====
    char* WL = smem;
    float* part = (float*)(smem + 131072);
    const int j0 = wg << 4;
    {
      const int R = tid >> 2, q = tid & 3;
      const int grow = ((R >> 4) << 10) + j0 + (R & 15);
      stage_row_q(A.Whh + (size_t)grow * HSZ + q * 256, WL + (size_t)R * 2048,
                  (R & 7) << 4, q);
    }
    const int uu = tid & 15, bb = tid >> 4;
    float cst[2];
    cst[0] = A.c0[(size_t)bb * HSZ + j0 + uu];
    cst[1] = A.c0[(size_t)(bb + 16) * HSZ + j0 + uu];
    __syncthreads();
    unsigned* myflag = A.bar + wg;

    for (int t = 0; t < TSZ; ++t) {
      float g0v[4][2];
      {
        const int col = t * 32;
#pragma unroll
        for (int g4 = 0; g4 < 4; ++g4) {
          const u16* gp = A.G0T + (size_t)((g4 << 10) + j0 + uu) * M4 + col;
          g0v[g4][0] = bf2f(gp[bb]);
          g0v[g4][1] = bf2f(gp[bb + 16]);
        }
      }
      if (t > 0) wait64(A.bar, (unsigned)t, l);
      const u16* hprev = A.H0 + (size_t)t * (BSZ * HSZ);
      const u16* hb = hprev + (size_t)(bh * 16 + l15) * HSZ + (kh << 9) + (lq << 3);
      short8 a[16];
      cohld16x16(hb, a);
      __builtin_amdgcn_sched_barrier(0);
      f32x4 acc[4];
      { f32x4 z = {0.f,0.f,0.f,0.f}; acc[0]=z; acc[1]=z; acc[2]=z; acc[3]=z; }
#pragma unroll
      for (int k = 0; k < 16; ++k) {
        const int kbyte = (((kh << 4) + k) << 6) + (lq << 4);
#pragma unroll
        for (int tr = 0; tr < 4; ++tr)
          acc[tr] = mfma16(a[k], ldsB(WL, (tr << 4) + l15, kbyte), acc[tr]);
      }
#pragma unroll
      for (int tr = 0; tr < 4; ++tr)
        part_wr(part, 10, wv, (tr << 4) + l15, lq, acc[tr]);
      __syncthreads();
      const bool last = (t == TSZ - 1);
      u16* hnext = A.H0 + (size_t)(t + 1) * (BSZ * HSZ);
      u16 hv[2];
#pragma unroll
      for (int pp = 0; pp < 2; ++pp) {
        const int b = bb + (pp << 4);
        float gi = g0v[0][pp], gf = g0v[1][pp], gg = g0v[2][pp], go = g0v[3][pp];
#pragma unroll
        for (int kh2 = 0; kh2 < 2; ++kh2) {
          const int w2 = (pp << 1) | kh2;
          gi += part_rd(part, 10, w2, uu, bb);
          gf += part_rd(part, 10, w2, 16 + uu, bb);
          gg += part_rd(part, 10, w2, 32 + uu, bb);
          go += part_rd(part, 10, w2, 48 + uu, bb);
        }
        float i_ = sigm(gi), f_ = sigm(gf), g_ = tanh_fast(gg), o_ = sigm(go);
        float c_ = f_ * cst[pp] + i_ * g_;
        cst[pp] = c_;
        float h_ = o_ * tanh_fast(c_);
        hv[pp] = f2bf(h_);
        if (last) {
          A.out_hc[(size_t)b * HSZ + j0 + uu] = h_;
          A.out_hc[2 * BSZ * HSZ + (size_t)b * HSZ + j0 + uu] = c_;
        }
      }
      cohst2_u16(hnext + (size_t)bb * HSZ + j0 + uu, hv[0],
                 hnext + (size_t)(bb + 16) * HSZ + j0 + uu, hv[1]);
      __syncthreads();
      if (tid == 0) flagst(myflag, (unsigned)(t + 1));
    }
  } else if (wg < NWRK) {
    // ===== layer 1 (round-9 structure; H1 time-major) =====
    char* WxL = smem;
    char* WhL = smem + 65536;
    float* part = (float*)(smem + 131072);
    float* biasL = (float*)(smem + 139264);
    const int lw = wg - 64;
    const int j1 = lw << 3;
    {
      const int rr = tid >> 2, q = tid & 3;
      const int r = rr & 31;
      const int grow = FH + ((r >> 3) << 10) + j1 + (r & 7);
      const float* base = (rr >= 32) ? A.Whh : A.Wih;
      char* dst = ((rr >= 32) ? WhL : WxL) + (size_t)r * 2048;
      stage_row_q(base + (size_t)grow * HSZ + q * 256, dst, (r & 7) << 4, q);
    }
    if (tid < 32) {
      const int grow = FH + ((tid >> 3) << 10) + j1 + (tid & 7);
      biasL[tid] = A.bih[grow] + A.bhh[grow];
    }
    const int uu = tid & 7, b1 = tid >> 3;
    float cst = A.c0[BSZ * HSZ + (size_t)b1 * HSZ + j1 + uu];
    __syncthreads();
    unsigned* myflag = A.bar + 64 + lw;

    for (int t = 0; t < TSZ; ++t) {
      wait64(A.bar, (unsigned)(t + 1), l);
      const u16* x1 = A.H0 + (size_t)(t + 1) * (BSZ * HSZ);
      const u16* xb = x1 + (size_t)(bh * 16 + l15) * HSZ + (kh << 9) + (lq << 3);
      short8 ax[16];
      cohld16x16(xb, ax);
      __builtin_amdgcn_sched_barrier(0);
      f32x4 acc[2];
      { f32x4 z = {0.f,0.f,0.f,0.f}; acc[0]=z; acc[1]=z; }
#pragma unroll
      for (int k = 0; k < 16; ++k) {
        const int kbyte = (((kh << 4) + k) << 6) + (lq << 4);
        acc[0] = mfma16(ax[k], ldsB(WxL, l15, kbyte), acc[0]);
        acc[1] = mfma16(ax[k], ldsB(WxL, 16 + l15, kbyte), acc[1]);
      }
      if (t > 0) wait128(A.bar + 64, (unsigned)t, l);
      const u16* hp = (t == 0) ? A.h1init : A.H1 + (size_t)(t - 1) * (BSZ * HSZ);
      const u16* hbp = hp + (size_t)(bh * 16 + l15) * HSZ + (kh << 9) + (lq << 3);
      short8 ah[16];
      cohld16x16(hbp, ah);
      __builtin_amdgcn_sched_barrier(0);
#pragma unroll
      for (int k = 0; k < 16; ++k) {
        const int kbyte = (((kh << 4) + k) << 6) + (lq << 4);
        acc[0] = mfma16(ah[k], ldsB(WhL, l15, kbyte), acc[0]);
        acc[1] = mfma16(ah[k], ldsB(WhL, 16 + l15, kbyte), acc[1]);
      }
#pragma unroll
      for (int tr = 0; tr < 2; ++tr)
        part_wr(part, 9, wv, (tr << 4) + l15, lq, acc[tr]);
      __syncthreads();
      const bool last = (t == TSZ - 1);
      {
        const int c = b1 & 15, ph = b1 >> 4;
        float gi = biasL[uu], gf = biasL[8 + uu], gg = biasL[16 + uu], go = biasL[24 + uu];
#pragma unroll
        for (int kh2 = 0; kh2 < 2; ++kh2) {
          const int w2 = (ph << 1) | kh2;
          gi += part_rd(part, 9, w2, uu, c);
          gf += part_rd(part, 9, w2, 8 + uu, c);
          gg += part_rd(part, 9, w2, 16 + uu, c);
          go += part_rd(part, 9, w2, 24 + uu, c);
        }
        float i_ = sigm(gi), f_ = sigm(gf), g_ = tanh_fast(gg), o_ = sigm(go);
        float c_ = f_ * cst + i_ * g_;
        cst = c_;
        float h_ = o_ * tanh_fast(c_);
        cohst1_u16(A.H1 + (size_t)t * (BSZ * HSZ) + (size_t)b1 * HSZ + j1 + uu, f2bf(h_));
        if (last) {
          A.out_hc[BSZ * HSZ + (size_t)b1 * HSZ + j1 + uu] = h_;
          A.out_hc[3 * BSZ * HSZ + (size_t)b1 * HSZ + j1 + uu] = c_;
        }
      }
      __syncthreads();
      if (tid == 0) flagst(myflag, (unsigned)(t + 1));
    }
  } else {
    // ===== converter + early-proj blocks =====
    const int cid = wg - NWRK;     // 0..63
    if (A.mode >= 1) {
      const int n4 = (int)((size_t)VSZ * HSZ / 4);
      const float4* src = (const float4*)A.Wout;
      ushort4* dst = (ushort4*)A.Woutbf;
      for (int i = cid * 256 + tid; i < n4; i += 64 * 256) {
        float4 v = src[i];
        ushort4 o;
        o.x = f2bf_hw(v.x); o.y = f2bf_hw(v.y); o.z = f2bf_hw(v.z); o.w = f2bf_hw(v.w);
        dst[i] = o;
      }
      asm volatile("s_waitcnt vmcnt(0)" ::: "memory");
      __builtin_amdgcn_fence(__ATOMIC_RELEASE, "agent");
      __syncthreads();
      if (tid == 0) flagst(A.bar + 192 + cid, 1u);
      if (A.mode == 2) {
        wait64(A.bar + 192, 1u, l);
        __syncthreads();
        for (int k = 0; k < CVT_PER; ++k) {
          const int w = cid + (k << 6);          // bm-ascending across blocks
          const int bm = w / NNT, bn = w % NNT;
          wait128(A.bar + 64, (unsigned)(4 * bm + 4), l);
          __syncthreads();
          gemm_tile<3, false, true>(smem, A.H1, A.Woutbf, A.Lbf, A.bout, A.rowsum,
                                    bm * 128, bn * 128, VSZ, HSZ, LDBF);
        }
      }
    }
  }
}

// ---------- logsumexp finish ----------
__global__ void lse_kernel(float* __restrict__ rowsum, int n) {
  int i = blockIdx.x * 256 + threadIdx.x;
  if (i < n) rowsum[i] = logf(rowsum[i]);
}

__global__ __launch_bounds__(256) void lsm_finish(float* __restrict__ C,
                                                  const float* __restrict__ lse, int Vd) {
  int row = blockIdx.y;
  size_t start = (size_t)row * (size_t)Vd;
  float s = lse[row];
  int i = blockIdx.x * 256 + threadIdx.x;
  int col = i * 4;
  if (col + 3 < Vd) {
    f32x4* p = (f32x4*)(C + start + col);
    f32x4 v = *p;
    v[0] -= s; v[1] -= s; v[2] -= s; v[3] -= s;
    *p = v;
  } else {
    for (int j = col; j < Vd; ++j) C[start + j] -= s;
  }
}

__global__ __launch_bounds__(256) void lsm_finish_bf(const u16* __restrict__ L,
                                                     float* __restrict__ out,
                                                     const float* __restrict__ rowsum,
                                                     int Vd, int ldl) {
  int row = blockIdx.y;
  float s = logf(rowsum[row]);
  int col = blockIdx.x * 2048 + threadIdx.x * 8;
  const u16* lp = L + (size_t)row * ldl;
  float* op = out + (size_t)row * Vd;
  if (col + 7 < Vd) {
    short8 v = *(const short8*)(lp + col);
    f32x4 a, b;
    a[0] = bf2f((u16)v[0]) - s; a[1] = bf2f((u16)v[1]) - s;
    a[2] = bf2f((u16)v[2]) - s; a[3] = bf2f((u16)v[3]) - s;
    b[0] = bf2f((u16)v[4]) - s; b[1] = bf2f((u16)v[5]) - s;
    b[2] = bf2f((u16)v[6]) - s; b[3] = bf2f((u16)v[7]) - s;
    *(f32x4*)(op + col) = a;
    *(f32x4*)(op + col + 4) = b;
  } else {
    for (int j = col; j < Vd; ++j) op[j] = bf2f(lp[j]) - s;
  }
}

// ---------- launcher ----------
extern "C" void kernel_launch(void* const* d_in, const int* in_sizes, int n_in,
                              void* d_out, int out_size, void* d_ws, size_t ws_size,
                              hipStream_t stream) {
  const int* tokens = (const int*)d_in[0];
  const float* emb = (const float*)d_in[1];
  const float* Wih = (const float*)d_in[2];
  const float* Whh = (const float*)d_in[3];
  const float* bih = (const float*)d_in[4];
  const float* bhh = (const float*)d_in[5];
  const float* Wout = (const float*)d_in[6];
  const float* bout = (const float*)d_in[7];
  const float* h0 = (const float*)d_in[8];
  const float* c0 = (const float*)d_in[9];
  float* out = (float*)d_out;

  char* w = (char*)d_ws;
  size_t o = 0;
  u16* Xbf = (u16*)(w + o);    o += (size_t)M4 * HSZ * 2;
  u16* Wih0bf = (u16*)(w + o); o += (size_t)FH * HSZ * 2;
  u16* G0T = (u16*)(w + o);    o += (size_t)FH * M4 * 2;
  u16* H0 = (u16*)(w + o);     o += (size_t)(TSZ + 1) * BSZ * HSZ * 2;
  u16* H1 = (u16*)(w + o);     o += (size_t)BSZ * TSZ * HSZ * 2;
  u16* h1init = (u16*)(w + o); o += (size_t)BSZ * HSZ * 2;
  float* bias0 = (float*)(w + o);  o += FH * 4;
  float* rowsum = (float*)(w + o); o += M4 * 4;
  unsigned* bar = (unsigned*)(w + o); o += 4096;
  u16* Woutbf = (u16*)(w + o);
  size_t need_full = o + (size_t)VSZ * HSZ * 2;
  u16* Lbf = (u16*)(w + need_full);
  size_t need_lbf = need_full + (size_t)M4 * LDBF * 2;
  const bool bcvt = (ws_size < need_full);
  const bool bf16c = (ws_size >= need_lbf);
  const int mode = bcvt ? 0 : (bf16c ? 2 : 1);

  prep_all<<<128, 256, 0, stream>>>(bih, bhh, bias0, rowsum, bar, h0, H0, h1init);
  cvt_bf16<<<2048, 256, 0, stream>>>(Wih, Wih0bf, FH * HSZ / 4);
  embed_kernel<<<M4, 256, 0, stream>>>(tokens, emb, Xbf);
  // G0T[4H][M4] = Wih0 @ X^T + (b_ih0 + b_hh0)
  gemm_bt<2, false, 0, false><<<32 * 32, 256, 0, stream>>>(
      Wih0bf, Xbf, G0T, bias0, nullptr, 32, 32, M4, HSZ, M4, 0);

  LstmArgs la{G0T, Wih, Whh, bih, bhh, c0, H0, H1, h1init,
              out + (size_t)OUT_LOGP, bar, Wout, Woutbf, Lbf, bout, rowsum, mode};
  void* kargs[] = {&la};
  hipFuncSetAttribute((const void*)lstm_coop, hipFuncAttributeMaxDynamicSharedMemorySize, LDSB);
  hipLaunchCooperativeKernel((const void*)lstm_coop, dim3(NBLK), dim3(256), kargs, LDSB, stream);

  const int TOT = 32 * NNT;   // 12576 proj tiles
  if (bf16c) {
    gemm_bt<3, false, 2, true><<<TOT - CVTILES, 256, 0, stream>>>(
        H1, Woutbf, Lbf, bout, rowsum, 32, NNT, VSZ, HSZ, LDBF, CVTILES);
    lsm_finish_bf<<<dim3(25, M4), 256, 0, stream>>>(Lbf, out, rowsum, VSZ, LDBF);
  } else if (!bcvt) {
    gemm_bt<1, false, 2, true><<<TOT, 256, 0, stream>>>(
        H1, Woutbf, out, bout, rowsum, 32, NNT, VSZ, HSZ, VSZ, 0);
    lse_kernel<<<16, 256, 0, stream>>>(rowsum, M4);
    lsm_finish<<<dim3((VSZ + 1023) / 1024, M4), 256, 0, stream>>>(out, rowsum, VSZ);
  } else {
    gemm_bt<1, true, 2, true><<<TOT, 256, 0, stream>>>(
        H1, Wout, out, bout, rowsum, 32, NNT, VSZ, HSZ, VSZ, 0);
    lse_kernel<<<16, 256, 0, stream>>>(rowsum, M4);
    lsm_finish<<<dim3((VSZ + 1023) / 1024, M4), 256, 0, stream>>>(out, rowsum, VSZ);
  }
}